// Round 4
// baseline (283.999 us; speedup 1.0000x reference)
//
#include <hip/hip_runtime.h>

// ---------------------------------------------------------------------------
// Wiener 3D patch filter, MI355X — channel-packed FFT version.
// 4 patches per 256-thread block; 6 complex LDS planes:
//   plane p (p=0..3): Z_p = fft2(a0_p + i*a1_p)   (later reused for Q_p)
//   plane 4+j (j=0,1): W_j = fft2(a2_{2j} + i*a2_{2j+1})  (later reused for R_j)
// Spectral middle does split -> ch-DFT -> Wiener gain -> inv ch-DFT ->
// hermitianization -> repack, per mirror-pair (k,-k).
// Overlap-add via 16 parity planes in d_ws (no atomics); atomic fallback.
// ---------------------------------------------------------------------------

constexpr float TWR[16] = {
  1.0f, 0.98078528040323044f, 0.92387953251128674f, 0.83146961230254524f,
  0.70710678118654752f, 0.55557023301960222f, 0.38268343236508977f, 0.19509032201612827f,
  0.0f, -0.19509032201612827f, -0.38268343236508977f, -0.55557023301960222f,
  -0.70710678118654752f, -0.83146961230254524f, -0.92387953251128674f, -0.98078528040323044f
};
constexpr float TWI[16] = {
  -0.0f, -0.19509032201612827f, -0.38268343236508977f, -0.55557023301960222f,
  -0.70710678118654752f, -0.83146961230254524f, -0.92387953251128674f, -0.98078528040323044f,
  -1.0f, -0.98078528040323044f, -0.92387953251128674f, -0.83146961230254524f,
  -0.70710678118654752f, -0.55557023301960222f, -0.38268343236508977f, -0.19509032201612827f
};
constexpr int REV5[32] = {0,16,8,24,4,20,12,28,2,18,10,26,6,22,14,30,
                          1,17,9,25,5,21,13,29,3,19,11,27,7,23,15,31};

constexpr float S3   = 0.86602540378443865f;  // sqrt(3)/2
constexpr float EPSF = 1e-15f;
constexpr float INV_WIN_DEN = -1.0f / 76.8f;  // -1/(0.3*16*16)

#define PLANE_FLOATS (4 * 3 * 512 * 512)             // 3,145,728 per parity plane
#define WS_NEEDED    ((size_t)16 * PLANE_FLOATS * 4) // 201,326,592 bytes

// ---- butterfly with compile-time twiddle specialization ----
template<int SIGN, int K>
__device__ __forceinline__ void bfly(float& ur, float& ui, float& vr, float& vi) {
  if constexpr (K == 0) {
    float tr = vr, ti = vi;
    vr = ur - tr; vi = ui - ti; ur += tr; ui += ti;
  } else if constexpr (K == 8) {
    float tr = (SIGN < 0) ?  vi : -vi;
    float ti = (SIGN < 0) ? -vr :  vr;
    vr = ur - tr; vi = ui - ti; ur += tr; ui += ti;
  } else {
    constexpr float wr = TWR[K];
    constexpr float wi = (SIGN < 0) ? TWI[K] : -TWI[K];
    float tr = wr * vr - wi * vi;
    float ti = wr * vi + wi * vr;
    vr = ur - tr; vi = ui - ti; ur += tr; ui += ti;
  }
}

template<int SIGN, int S, int J>
__device__ __forceinline__ void stage_j(float* ar, float* ai) {
  constexpr int m = 1 << S, h = m >> 1, ts = 32 >> S;
  if constexpr (J < h) {
    #pragma unroll
    for (int k = 0; k < 32; k += m)
      bfly<SIGN, J * ts>(ar[k + J], ai[k + J], ar[k + J + h], ai[k + J + h]);
    stage_j<SIGN, S, J + 1>(ar, ai);
  }
}

template<int SIGN>
__device__ __forceinline__ void fft32(float* ar, float* ai) {
  stage_j<SIGN, 1, 0>(ar, ai);
  stage_j<SIGN, 2, 0>(ar, ai);
  stage_j<SIGN, 3, 0>(ar, ai);
  stage_j<SIGN, 4, 0>(ar, ai);
  stage_j<SIGN, 5, 0>(ar, ai);
}

// reflect-pad index mapping for v in [-32, 543], N=512 (mode='reflect')
__device__ __forceinline__ int refl(int v) {
  v = (v < 0) ? -v : v;
  return (v >= 512) ? (1022 - v) : v;
}

#define LSTR 33            // padded LDS row stride (floats)
#define PL (32*LSTR)       // complex plane = 1056 floats per (re/im) array

// MODE 0: atomicAdd into out (fallback).  MODE 1: plain store into parity plane.
template<int MODE>
__global__ __launch_bounds__(256)
void wiener_patch(const float* __restrict__ I,
                  const float* __restrict__ S,
                  float* __restrict__ dst)
{
  __shared__ float sre[6 * PL];
  __shared__ float sim[6 * PL];
  __shared__ float w1[32];
  __shared__ float red[24];      // [p*6 + {I0,I1,I2,S0,S1,S2}]
  __shared__ float sw2s;
  __shared__ int   pgeo[16];     // [p*4 + {py,px,b,parity-plane}]

  const int t  = threadIdx.x;
  const int q  = t >> 6;          // patch slot 0..3 (wave == patch)
  const int tl = t & 63;

  if (t < 32) { float tt = (float)t - 15.5f; w1[t] = __expf(tt * tt * INV_WIN_DEN); }
  if (t < 4) {
    int pp = blockIdx.x * 4 + t;
    int ppx = pp % 67 + 1;  pp /= 67;
    int ppy = pp % 67 + 1;
    int pb  = pp / 67;
    pgeo[t*4+0] = ppy; pgeo[t*4+1] = ppx; pgeo[t*4+2] = pb;
    pgeo[t*4+3] = ((ppy & 3) << 2) | (ppx & 3);
  }
  __syncthreads();
  if (t == 0) {
    float s2 = 0.f;
    #pragma unroll
    for (int k = 0; k < 32; ++k) s2 += w1[k] * w1[k];
    float mw = s2 * (1.f/32.f);
    sw2s = mw * mw;               // (mean win^2)^2 helper
  }

  // ---- load: 64 threads per patch; a0->sre[q], a1->sim[q], a2->W plane ----
  const int py = pgeo[q*4+0], px = pgeo[q*4+1], b = pgeo[q*4+2];
  float sI0=0.f,sI1=0.f,sI2=0.f,sS0=0.f,sS1=0.f,sS2=0.f;
  {
    const int gy0 = py * 8 - 32, gx0 = px * 8 - 32;
    const int x  = tl & 31;
    const int y0 = tl >> 5;       // 0/1; rows y0+2i
    const int rx = refl(gx0 + x);
    const size_t bbase = (size_t)b * 3 * 262144;
    const int zb = q * PL;
    const int wb = (4 + (q >> 1)) * PL;
    float* aw2 = (q & 1) ? sim : sre;
    #pragma unroll
    for (int i = 0; i < 16; ++i) {
      int y  = y0 + 2 * i;
      int ry = refl(gy0 + y);
      size_t g = bbase + (size_t)ry * 512 + rx;
      float v0 = I[g];            float u0 = S[g];
      float v1 = I[g + 262144];   float u1 = S[g + 262144];
      float v2 = I[g + 524288];   float u2 = S[g + 524288];
      sI0 += v0; sI1 += v1; sI2 += v2;
      sS0 += u0; sS1 += u1; sS2 += u2;
      int l = y * LSTR + x;
      sre[zb + l] = v0; sim[zb + l] = v1; aw2[wb + l] = v2;
    }
  }
  #pragma unroll
  for (int off = 32; off > 0; off >>= 1) {
    sI0 += __shfl_down(sI0, off); sI1 += __shfl_down(sI1, off); sI2 += __shfl_down(sI2, off);
    sS0 += __shfl_down(sS0, off); sS1 += __shfl_down(sS1, off); sS2 += __shfl_down(sS2, off);
  }
  if (tl == 0) {                  // wave == patch: direct write, no atomics
    red[q*6+0] = sI0; red[q*6+1] = sI1; red[q*6+2] = sI2;
    red[q*6+3] = sS0; red[q*6+4] = sS1; red[q*6+5] = sS2;
  }
  __syncthreads();

  // ---- forward row FFTs: 6 transforms x 32 rows (window ×0.5 folded) ----
  if (t < 192) {
    const int T = t >> 5, row = t & 31;
    float ma, mb;
    if (T < 4) { ma = red[T*6+0] * (1.f/1024.f); mb = red[T*6+1] * (1.f/1024.f); }
    else { int j = T - 4; ma = red[(2*j)*6+2] * (1.f/1024.f); mb = red[(2*j+1)*6+2] * (1.f/1024.f); }
    const int rb = T * PL + row * LSTR;
    const float hw = 0.5f * w1[row];
    float ar[32], ai[32];
    #pragma unroll
    for (int i = 0; i < 32; ++i) {
      const int xs = REV5[i];
      const float wv = hw * w1[xs];
      ar[i] = (sre[rb + xs] - ma) * wv;
      ai[i] = (sim[rb + xs] - mb) * wv;
    }
    fft32<-1>(ar, ai);
    #pragma unroll
    for (int i = 0; i < 32; ++i) { sre[rb + i] = ar[i]; sim[rb + i] = ai[i]; }
  }
  __syncthreads();

  // ---- forward col FFTs ----
  if (t < 192) {
    const int T = t >> 5, col = t & 31;
    const int cb = T * PL + col;
    float ar[32], ai[32];
    #pragma unroll
    for (int i = 0; i < 32; ++i) { const int ys = REV5[i]; ar[i] = sre[cb + LSTR*ys]; ai[i] = sim[cb + LSTR*ys]; }
    fft32<-1>(ar, ai);
    #pragma unroll
    for (int i = 0; i < 32; ++i) { sre[cb + LSTR*i] = ar[i]; sim[cb + LSTR*i] = ai[i]; }
  }
  __syncthreads();

  // ---- spectral middle: each task owns mirror-pair (k, m=-k) of one pair j.
  // Enumeration (514 tasks per pair, exact cover, race-free in-place):
  //   u<480: kx=1+u%15 (1..15), ky=u/15 (0..31); mirror has mx=17..31.
  //   u>=480: e=u-480 (0..33): kx = e<17 ? 0 : 16, ky = e%17 (0..16).
  for (int task = t; task < 1028; task += 256) {
    const int j = (task >= 514) ? 1 : 0;
    const int u = task - j * 514;
    int ky, kx;
    if (u < 480) { ky = u / 15; kx = 1 + (u - ky * 15); }
    else { int e = u - 480; kx = (e >= 17) ? 16 : 0; ky = (e >= 17) ? (e - 17) : e; }
    const int my = (32 - ky) & 31, mx = (32 - kx) & 31;
    const int ok = ky * LSTR + kx, om = my * LSTR + mx;
    const int zp0 = (2*j) * PL, zp1 = zp0 + PL, wp = (4 + j) * PL;
    const float Wkr = sre[wp+ok], Wki = sim[wp+ok], Wmr = sre[wp+om], Wmi = sim[wp+om];
    float B2r[2], B2i[2];
    #pragma unroll
    for (int lp = 0; lp < 2; ++lp) {
      const int zp = lp ? zp1 : zp0;
      const float Zkr = sre[zp+ok], Zki = sim[zp+ok], Zmr = sre[zp+om], Zmi = sim[zp+om];
      // Hermitian splits (x2 true scale; 0.5 was folded into forward window)
      const float F0r = Zkr + Zmr, F0i = Zki - Zmi;
      const float F1r = Zki + Zmi, F1i = Zmr - Zkr;
      const float F2r = lp ? (Wki + Wmi) : (Wkr + Wmr);
      const float F2i = lp ? (Wmr - Wkr) : (Wki - Wmi);
      // forward channel DFT (w = e^{-2pi i/3})
      const float Spr = F1r+F2r, Spi = F1i+F2i, Smr = F1r-F2r, Smi = F1i-F2i;
      const float A0r = F0r + Spr,      A0i = F0i + Spi;
      const float t1r = F0r - 0.5f*Spr, t1i = F0i - 0.5f*Spi;
      const float A1r = t1r + S3*Smi,   A1i = t1i - S3*Smr;
      const float A2r = t1r - S3*Smi,   A2i = t1i + S3*Smr;
      const float P0 = A0r*A0r + A0i*A0i + EPSF;
      const float P1 = A1r*A1r + A1i*A1i + EPSF;
      const float P2 = A2r*A2r + A2i*A2i + EPSF;
      // Wiener gains (Pvv indexed by channel-frequency, reference quirk);
      // mirror side: P1(m)=P2(k), P2(m)=P1(k)
      const int p = 2*j + lp;
      const float cs  = sw2s * (1.f/1024.f);
      const float s0 = red[p*6+3], s1 = red[p*6+4], s2v = red[p*6+5];
      const float Pv0 = cs*s0*s0, Pv1 = cs*s1*s1, Pv2 = cs*s2v*s2v;
      const float H0  = fmaxf(P0 - Pv0, 0.f) / P0;
      const float H1k = fmaxf(P1 - Pv1, 0.f) / P1;
      const float H2k = fmaxf(P2 - Pv2, 0.f) / P2;
      const float H1m = fmaxf(P2 - Pv1, 0.f) / P2;
      const float H2m = fmaxf(P1 - Pv2, 0.f) / P1;
      // k side: G = H .* A ; inverse channel DFT (u = e^{+2pi i/3}, no 1/3)
      float G0r = H0*A0r,  G0i = H0*A0i;
      float G1r = H1k*A1r, G1i = H1k*A1i;
      float G2r = H2k*A2r, G2i = H2k*A2i;
      float Qpr = G1r+G2r, Qpi = G1i+G2i, Qmr = G1r-G2r, Qmi = G1i-G2i;
      const float M0kr = G0r + Qpr,      M0ki = G0i + Qpi;
      float u1r = G0r - 0.5f*Qpr,        u1i = G0i - 0.5f*Qpi;
      const float M1kr = u1r - S3*Qmi,   M1ki = u1i + S3*Qmr;
      const float M2kr = u1r + S3*Qmi,   M2ki = u1i - S3*Qmr;
      // m side: F^(m): A0->conj(A0), A1->conj(A2), A2->conj(A1)
      G0r = H0*A0r;   G0i = -H0*A0i;
      G1r = H1m*A2r;  G1i = -H1m*A2i;
      G2r = H2m*A1r;  G2i = -H2m*A1i;
      Qpr = G1r+G2r;  Qpi = G1i+G2i;  Qmr = G1r-G2r;  Qmi = G1i-G2i;
      const float M0mr = G0r + Qpr,      M0mi = G0i + Qpi;
      u1r = G0r - 0.5f*Qpr;              u1i = G0i - 0.5f*Qpi;
      const float M1mr = u1r - S3*Qmi,   M1mi = u1i + S3*Qmr;
      const float M2mr = u1r + S3*Qmi,   M2mi = u1i - S3*Qmr;
      // Hermitian parts ×2 (the 1/2 is folded into the epilogue 1/6144)
      const float B0r = M0kr + M0mr, B0i = M0ki - M0mi;
      const float B1r = M1kr + M1mr, B1i = M1ki - M1mi;
      B2r[lp] = M2kr + M2mr;  B2i[lp] = M2ki - M2mi;
      // pack Q = H0 + i*H1, in place over Z plane (task owns both k and m)
      sre[zp+ok] = B0r - B1i;  sim[zp+ok] = B0i + B1r;
      sre[zp+om] = B0r + B1i;  sim[zp+om] = B1r - B0i;
    }
    // pack R = H2_{p0} + i*H2_{p1} over W plane
    sre[wp+ok] = B2r[0] - B2i[1];  sim[wp+ok] = B2i[0] + B2r[1];
    sre[wp+om] = B2r[0] + B2i[1];  sim[wp+om] = B2r[1] - B2i[0];
  }
  __syncthreads();

  // ---- inverse col FFTs ----
  if (t < 192) {
    const int T = t >> 5, col = t & 31;
    const int cb = T * PL + col;
    float ar[32], ai[32];
    #pragma unroll
    for (int i = 0; i < 32; ++i) { const int ys = REV5[i]; ar[i] = sre[cb + LSTR*ys]; ai[i] = sim[cb + LSTR*ys]; }
    fft32<+1>(ar, ai);
    #pragma unroll
    for (int i = 0; i < 32; ++i) { sre[cb + LSTR*i] = ar[i]; sim[cb + LSTR*i] = ai[i]; }
  }
  __syncthreads();

  // ---- inverse row FFTs (need both re and im) ----
  if (t < 192) {
    const int T = t >> 5, row = t & 31;
    const int rb = T * PL + row * LSTR;
    float ar[32], ai[32];
    #pragma unroll
    for (int i = 0; i < 32; ++i) { const int xs = REV5[i]; ar[i] = sre[rb + xs]; ai[i] = sim[rb + xs]; }
    fft32<+1>(ar, ai);
    #pragma unroll
    for (int i = 0; i < 32; ++i) { sre[rb + i] = ar[i]; sim[rb + i] = ai[i]; }
  }
  __syncthreads();

  // ---- epilogue: out0=Re(Q), out1=Im(Q), out2=Re/Im(R); window + mean ----
  for (int jj = t; jj < 12288; jj += 256) {
    const int x2 = jj & 31, y2 = (jj >> 5) & 31;
    const int rest = jj >> 10;          // 0..11, wave-uniform
    const int p = rest & 3, c = rest >> 2;
    const int ppy = pgeo[p*4+0], ppx = pgeo[p*4+1], pb = pgeo[p*4+2];
    const int oy = ppy * 8 + y2 - 32, ox = ppx * 8 + x2 - 32;
    if (oy >= 0 && oy < 512 && ox >= 0 && ox < 512) {
      const int l = y2 * LSTR + x2;
      float v;
      if (c == 0)      v = sre[p * PL + l];
      else if (c == 1) v = sim[p * PL + l];
      else             v = ((p & 1) ? sim : sre)[(4 + (p >> 1)) * PL + l];
      const float wv = w1[y2] * w1[x2];               // win == win_interp
      const float mc = red[p*6 + c] * (1.f/1024.f);
      const float val = (v * (1.f/6144.f) + mc * wv) * wv;
      const size_t off = (((size_t)pb * 3 + c) * 512 + oy) * 512 + ox;
      if (MODE == 1) dst[(size_t)pgeo[p*4+3] * PLANE_FLOATS + off] = val;
      else           atomicAdd(dst + off, val);
    }
  }
}

// mask(y,x) = mrow(y%8) * mrow(x%8), mrow(r) = sum_k w1[r+8k]^2
__device__ __forceinline__ float mask_row(int r) {
  float m = 0.f;
  #pragma unroll
  for (int k = 0; k < 4; ++k) {
    float tt = (float)(r + 8 * k) - 15.5f;
    float w = __expf(tt * tt * INV_WIN_DEN);
    m += w * w;
  }
  return m;
}

// MODE1 phase 2: out = (sum of 16 planes + eps) / (mask + eps)
__global__ void wiener_combine(const float* __restrict__ ws, float* __restrict__ out)
{
  const int i = blockIdx.x * 256 + threadIdx.x;   // out_size = 3,145,728
  const int xx = i & 511;
  const int yy = (i >> 9) & 511;
  float s = 0.f;
  #pragma unroll
  for (int p = 0; p < 16; ++p) s += ws[(size_t)p * PLANE_FLOATS + i];
  out[i] = (s + EPSF) / (mask_row(yy & 7) * mask_row(xx & 7) + EPSF);
}

// MODE0 phase 2: in-place normalize after atomic accumulation
__global__ void wiener_norm(float* __restrict__ out)
{
  const int i = blockIdx.x * 256 + threadIdx.x;
  const int xx = i & 511;
  const int yy = (i >> 9) & 511;
  out[i] = (out[i] + EPSF) / (mask_row(yy & 7) * mask_row(xx & 7) + EPSF);
}

extern "C" void kernel_launch(void* const* d_in, const int* in_sizes, int n_in,
                              void* d_out, int out_size, void* d_ws, size_t ws_size,
                              hipStream_t stream)
{
  const float* I = (const float*)d_in[0];
  const float* S = (const float*)d_in[1];
  float* out = (float*)d_out;
  const int nblocks = (4 * 67 * 67) / 4;   // 4 patches per block, 4489 blocks

  if (ws_size >= WS_NEEDED && d_ws != nullptr) {
    float* ws = (float*)d_ws;
    // every in-crop plane pixel is written exactly once -> no zeroing needed
    wiener_patch<1><<<dim3(nblocks), dim3(256), 0, stream>>>(I, S, ws);
    wiener_combine<<<dim3(out_size / 256), dim3(256), 0, stream>>>(ws, out);
  } else {
    hipMemsetAsync(out, 0, (size_t)out_size * sizeof(float), stream);
    wiener_patch<0><<<dim3(nblocks), dim3(256), 0, stream>>>(I, S, out);
    wiener_norm<<<dim3(out_size / 256), dim3(256), 0, stream>>>(out);
  }
}

// Round 5
// 280.218 us; speedup vs baseline: 1.0135x; 1.0135x over previous
//
#include <hip/hip_runtime.h>

// ---------------------------------------------------------------------------
// Wiener 3D patch filter, MI355X — channel-packed FFT version.
// 4 patches per 256-thread block; 6 complex LDS planes:
//   plane p (p=0..3): Z_p = fft2(a0_p + i*a1_p)   (later reused for Q_p)
//   plane 4+j (j=0,1): W_j = fft2(a2_{2j} + i*a2_{2j+1})  (later reused for R_j)
// Spectral middle does split -> ch-DFT -> Wiener gain -> inv ch-DFT ->
// hermitianization -> repack, per mirror-pair (k,-k).
// Task enumeration is bank-aware: consecutive lanes walk ky (stride-33
// addresses -> all 32 banks distinct), not kx.
// Overlap-add via 16 parity planes in d_ws (no atomics); atomic fallback.
// ---------------------------------------------------------------------------

constexpr float TWR[16] = {
  1.0f, 0.98078528040323044f, 0.92387953251128674f, 0.83146961230254524f,
  0.70710678118654752f, 0.55557023301960222f, 0.38268343236508977f, 0.19509032201612827f,
  0.0f, -0.19509032201612827f, -0.38268343236508977f, -0.55557023301960222f,
  -0.70710678118654752f, -0.83146961230254524f, -0.92387953251128674f, -0.98078528040323044f
};
constexpr float TWI[16] = {
  -0.0f, -0.19509032201612827f, -0.38268343236508977f, -0.55557023301960222f,
  -0.70710678118654752f, -0.83146961230254524f, -0.92387953251128674f, -0.98078528040323044f,
  -1.0f, -0.98078528040323044f, -0.92387953251128674f, -0.83146961230254524f,
  -0.70710678118654752f, -0.55557023301960222f, -0.38268343236508977f, -0.19509032201612827f
};
constexpr int REV5[32] = {0,16,8,24,4,20,12,28,2,18,10,26,6,22,14,30,
                          1,17,9,25,5,21,13,29,3,19,11,27,7,23,15,31};

constexpr float S3   = 0.86602540378443865f;  // sqrt(3)/2
constexpr float EPSF = 1e-15f;
constexpr float INV_WIN_DEN = -1.0f / 76.8f;  // -1/(0.3*16*16)

#define PLANE_FLOATS (4 * 3 * 512 * 512)             // 3,145,728 per parity plane
#define WS_NEEDED    ((size_t)16 * PLANE_FLOATS * 4) // 201,326,592 bytes

// ---- butterfly with compile-time twiddle specialization ----
template<int SIGN, int K>
__device__ __forceinline__ void bfly(float& ur, float& ui, float& vr, float& vi) {
  if constexpr (K == 0) {
    float tr = vr, ti = vi;
    vr = ur - tr; vi = ui - ti; ur += tr; ui += ti;
  } else if constexpr (K == 8) {
    float tr = (SIGN < 0) ?  vi : -vi;
    float ti = (SIGN < 0) ? -vr :  vr;
    vr = ur - tr; vi = ui - ti; ur += tr; ui += ti;
  } else {
    constexpr float wr = TWR[K];
    constexpr float wi = (SIGN < 0) ? TWI[K] : -TWI[K];
    float tr = wr * vr - wi * vi;
    float ti = wr * vi + wi * vr;
    vr = ur - tr; vi = ui - ti; ur += tr; ui += ti;
  }
}

template<int SIGN, int S, int J>
__device__ __forceinline__ void stage_j(float* ar, float* ai) {
  constexpr int m = 1 << S, h = m >> 1, ts = 32 >> S;
  if constexpr (J < h) {
    #pragma unroll
    for (int k = 0; k < 32; k += m)
      bfly<SIGN, J * ts>(ar[k + J], ai[k + J], ar[k + J + h], ai[k + J + h]);
    stage_j<SIGN, S, J + 1>(ar, ai);
  }
}

template<int SIGN>
__device__ __forceinline__ void fft32(float* ar, float* ai) {
  stage_j<SIGN, 1, 0>(ar, ai);
  stage_j<SIGN, 2, 0>(ar, ai);
  stage_j<SIGN, 3, 0>(ar, ai);
  stage_j<SIGN, 4, 0>(ar, ai);
  stage_j<SIGN, 5, 0>(ar, ai);
}

// reflect-pad index mapping for v in [-32, 543], N=512 (mode='reflect')
__device__ __forceinline__ int refl(int v) {
  v = (v < 0) ? -v : v;
  return (v >= 512) ? (1022 - v) : v;
}

#define LSTR 33            // padded LDS row stride (floats)
#define PL (32*LSTR)       // complex plane = 1056 floats per (re/im) array

// MODE 0: atomicAdd into out (fallback).  MODE 1: plain store into parity plane.
template<int MODE>
__global__ __launch_bounds__(256)
void wiener_patch(const float* __restrict__ I,
                  const float* __restrict__ S,
                  float* __restrict__ dst)
{
  __shared__ float sre[6 * PL];
  __shared__ float sim[6 * PL];
  __shared__ float w1[32];
  __shared__ float red[24];      // [p*6 + {I0,I1,I2,S0,S1,S2}]
  __shared__ float sw2s;
  __shared__ int   pgeo[16];     // [p*4 + {py,px,b,parity-plane}]

  const int t  = threadIdx.x;
  const int q  = t >> 6;          // patch slot 0..3 (wave == patch)
  const int tl = t & 63;

  if (t < 32) { float tt = (float)t - 15.5f; w1[t] = __expf(tt * tt * INV_WIN_DEN); }
  if (t < 4) {
    int pp = blockIdx.x * 4 + t;
    int ppx = pp % 67 + 1;  pp /= 67;
    int ppy = pp % 67 + 1;
    int pb  = pp / 67;
    pgeo[t*4+0] = ppy; pgeo[t*4+1] = ppx; pgeo[t*4+2] = pb;
    pgeo[t*4+3] = ((ppy & 3) << 2) | (ppx & 3);
  }
  __syncthreads();
  if (t == 0) {
    float s2 = 0.f;
    #pragma unroll
    for (int k = 0; k < 32; ++k) s2 += w1[k] * w1[k];
    float mw = s2 * (1.f/32.f);
    sw2s = mw * mw;               // (mean win^2)^2 helper
  }

  // ---- load: 64 threads per patch; a0->sre[q], a1->sim[q], a2->W plane ----
  const int py = pgeo[q*4+0], px = pgeo[q*4+1], b = pgeo[q*4+2];
  float sI0=0.f,sI1=0.f,sI2=0.f,sS0=0.f,sS1=0.f,sS2=0.f;
  {
    const int gy0 = py * 8 - 32, gx0 = px * 8 - 32;
    const int x  = tl & 31;
    const int y0 = tl >> 5;       // 0/1; rows y0+2i
    const int rx = refl(gx0 + x);
    const size_t bbase = (size_t)b * 3 * 262144;
    const int zb = q * PL;
    const int wb = (4 + (q >> 1)) * PL;
    float* aw2 = (q & 1) ? sim : sre;
    #pragma unroll
    for (int i = 0; i < 16; ++i) {
      int y  = y0 + 2 * i;
      int ry = refl(gy0 + y);
      size_t g = bbase + (size_t)ry * 512 + rx;
      float v0 = I[g];            float u0 = S[g];
      float v1 = I[g + 262144];   float u1 = S[g + 262144];
      float v2 = I[g + 524288];   float u2 = S[g + 524288];
      sI0 += v0; sI1 += v1; sI2 += v2;
      sS0 += u0; sS1 += u1; sS2 += u2;
      int l = y * LSTR + x;
      sre[zb + l] = v0; sim[zb + l] = v1; aw2[wb + l] = v2;
    }
  }
  #pragma unroll
  for (int off = 32; off > 0; off >>= 1) {
    sI0 += __shfl_down(sI0, off); sI1 += __shfl_down(sI1, off); sI2 += __shfl_down(sI2, off);
    sS0 += __shfl_down(sS0, off); sS1 += __shfl_down(sS1, off); sS2 += __shfl_down(sS2, off);
  }
  if (tl == 0) {                  // wave == patch: direct write, no atomics
    red[q*6+0] = sI0; red[q*6+1] = sI1; red[q*6+2] = sI2;
    red[q*6+3] = sS0; red[q*6+4] = sS1; red[q*6+5] = sS2;
  }
  __syncthreads();

  // ---- forward row FFTs: 6 transforms x 32 rows (window ×0.5 folded) ----
  if (t < 192) {
    const int T = t >> 5, row = t & 31;
    float ma, mb;
    if (T < 4) { ma = red[T*6+0] * (1.f/1024.f); mb = red[T*6+1] * (1.f/1024.f); }
    else { int j = T - 4; ma = red[(2*j)*6+2] * (1.f/1024.f); mb = red[(2*j+1)*6+2] * (1.f/1024.f); }
    const int rb = T * PL + row * LSTR;
    const float hw = 0.5f * w1[row];
    float ar[32], ai[32];
    #pragma unroll
    for (int i = 0; i < 32; ++i) {
      const int xs = REV5[i];
      const float wv = hw * w1[xs];
      ar[i] = (sre[rb + xs] - ma) * wv;
      ai[i] = (sim[rb + xs] - mb) * wv;
    }
    fft32<-1>(ar, ai);
    #pragma unroll
    for (int i = 0; i < 32; ++i) { sre[rb + i] = ar[i]; sim[rb + i] = ai[i]; }
  }
  __syncthreads();

  // ---- forward col FFTs ----
  if (t < 192) {
    const int T = t >> 5, col = t & 31;
    const int cb = T * PL + col;
    float ar[32], ai[32];
    #pragma unroll
    for (int i = 0; i < 32; ++i) { const int ys = REV5[i]; ar[i] = sre[cb + LSTR*ys]; ai[i] = sim[cb + LSTR*ys]; }
    fft32<-1>(ar, ai);
    #pragma unroll
    for (int i = 0; i < 32; ++i) { sre[cb + LSTR*i] = ar[i]; sim[cb + LSTR*i] = ai[i]; }
  }
  __syncthreads();

  // ---- spectral middle: each task owns mirror-pair (k, m=-k) of one pair j.
  // Bank-aware enumeration (514 tasks per pair, exact cover, race-free):
  //   u<480: ky = u & 31 (lanes walk ky -> stride-33 addrs -> distinct banks),
  //          kx = 1 + (u >> 5)  (1..15).
  //   u>=480: e=u-480 (0..33): kx = e<17 ? 0 : 16, ky = e%17 (0..16).
  for (int task = t; task < 1028; task += 256) {
    const int j = (task >= 514) ? 1 : 0;
    const int u = task - j * 514;
    int ky, kx;
    if (u < 480) { ky = u & 31; kx = 1 + (u >> 5); }
    else { int e = u - 480; kx = (e >= 17) ? 16 : 0; ky = (e >= 17) ? (e - 17) : e; }
    const int my = (32 - ky) & 31, mx = (32 - kx) & 31;
    const int ok = ky * LSTR + kx, om = my * LSTR + mx;
    const int zp0 = (2*j) * PL, zp1 = zp0 + PL, wp = (4 + j) * PL;
    const float Wkr = sre[wp+ok], Wki = sim[wp+ok], Wmr = sre[wp+om], Wmi = sim[wp+om];
    float B2r[2], B2i[2];
    #pragma unroll
    for (int lp = 0; lp < 2; ++lp) {
      const int zp = lp ? zp1 : zp0;
      const float Zkr = sre[zp+ok], Zki = sim[zp+ok], Zmr = sre[zp+om], Zmi = sim[zp+om];
      // Hermitian splits (x2 true scale; 0.5 was folded into forward window)
      const float F0r = Zkr + Zmr, F0i = Zki - Zmi;
      const float F1r = Zki + Zmi, F1i = Zmr - Zkr;
      const float F2r = lp ? (Wki + Wmi) : (Wkr + Wmr);
      const float F2i = lp ? (Wmr - Wkr) : (Wki - Wmi);
      // forward channel DFT (w = e^{-2pi i/3})
      const float Spr = F1r+F2r, Spi = F1i+F2i, Smr = F1r-F2r, Smi = F1i-F2i;
      const float A0r = F0r + Spr,      A0i = F0i + Spi;
      const float t1r = F0r - 0.5f*Spr, t1i = F0i - 0.5f*Spi;
      const float A1r = t1r + S3*Smi,   A1i = t1i - S3*Smr;
      const float A2r = t1r - S3*Smi,   A2i = t1i + S3*Smr;
      const float P0 = A0r*A0r + A0i*A0i + EPSF;
      const float P1 = A1r*A1r + A1i*A1i + EPSF;
      const float P2 = A2r*A2r + A2i*A2i + EPSF;
      // Wiener gains (Pvv indexed by channel-frequency, reference quirk);
      // mirror side: P1(m)=P2(k), P2(m)=P1(k)
      const int p = 2*j + lp;
      const float cs  = sw2s * (1.f/1024.f);
      const float s0 = red[p*6+3], s1 = red[p*6+4], s2v = red[p*6+5];
      const float Pv0 = cs*s0*s0, Pv1 = cs*s1*s1, Pv2 = cs*s2v*s2v;
      const float H0  = fmaxf(P0 - Pv0, 0.f) / P0;
      const float H1k = fmaxf(P1 - Pv1, 0.f) / P1;
      const float H2k = fmaxf(P2 - Pv2, 0.f) / P2;
      const float H1m = fmaxf(P2 - Pv1, 0.f) / P2;
      const float H2m = fmaxf(P1 - Pv2, 0.f) / P1;
      // k side: G = H .* A ; inverse channel DFT (u = e^{+2pi i/3}, no 1/3)
      float G0r = H0*A0r,  G0i = H0*A0i;
      float G1r = H1k*A1r, G1i = H1k*A1i;
      float G2r = H2k*A2r, G2i = H2k*A2i;
      float Qpr = G1r+G2r, Qpi = G1i+G2i, Qmr = G1r-G2r, Qmi = G1i-G2i;
      const float M0kr = G0r + Qpr,      M0ki = G0i + Qpi;
      float u1r = G0r - 0.5f*Qpr,        u1i = G0i - 0.5f*Qpi;
      const float M1kr = u1r - S3*Qmi,   M1ki = u1i + S3*Qmr;
      const float M2kr = u1r + S3*Qmi,   M2ki = u1i - S3*Qmr;
      // m side: F^(m): A0->conj(A0), A1->conj(A2), A2->conj(A1)
      G0r = H0*A0r;   G0i = -H0*A0i;
      G1r = H1m*A2r;  G1i = -H1m*A2i;
      G2r = H2m*A1r;  G2i = -H2m*A1i;
      Qpr = G1r+G2r;  Qpi = G1i+G2i;  Qmr = G1r-G2r;  Qmi = G1i-G2i;
      const float M0mr = G0r + Qpr,      M0mi = G0i + Qpi;
      u1r = G0r - 0.5f*Qpr;              u1i = G0i - 0.5f*Qpi;
      const float M1mr = u1r - S3*Qmi,   M1mi = u1i + S3*Qmr;
      const float M2mr = u1r + S3*Qmi,   M2mi = u1i - S3*Qmr;
      // Hermitian parts ×2 (the 1/2 is folded into the epilogue 1/6144)
      const float B0r = M0kr + M0mr, B0i = M0ki - M0mi;
      const float B1r = M1kr + M1mr, B1i = M1ki - M1mi;
      B2r[lp] = M2kr + M2mr;  B2i[lp] = M2ki - M2mi;
      // pack Q = H0 + i*H1, in place over Z plane (task owns both k and m)
      sre[zp+ok] = B0r - B1i;  sim[zp+ok] = B0i + B1r;
      sre[zp+om] = B0r + B1i;  sim[zp+om] = B1r - B0i;
    }
    // pack R = H2_{p0} + i*H2_{p1} over W plane
    sre[wp+ok] = B2r[0] - B2i[1];  sim[wp+ok] = B2i[0] + B2r[1];
    sre[wp+om] = B2r[0] + B2i[1];  sim[wp+om] = B2r[1] - B2i[0];
  }
  __syncthreads();

  // ---- inverse col FFTs ----
  if (t < 192) {
    const int T = t >> 5, col = t & 31;
    const int cb = T * PL + col;
    float ar[32], ai[32];
    #pragma unroll
    for (int i = 0; i < 32; ++i) { const int ys = REV5[i]; ar[i] = sre[cb + LSTR*ys]; ai[i] = sim[cb + LSTR*ys]; }
    fft32<+1>(ar, ai);
    #pragma unroll
    for (int i = 0; i < 32; ++i) { sre[cb + LSTR*i] = ar[i]; sim[cb + LSTR*i] = ai[i]; }
  }
  __syncthreads();

  // ---- inverse row FFTs (need both re and im) ----
  if (t < 192) {
    const int T = t >> 5, row = t & 31;
    const int rb = T * PL + row * LSTR;
    float ar[32], ai[32];
    #pragma unroll
    for (int i = 0; i < 32; ++i) { const int xs = REV5[i]; ar[i] = sre[rb + xs]; ai[i] = sim[rb + xs]; }
    fft32<+1>(ar, ai);
    #pragma unroll
    for (int i = 0; i < 32; ++i) { sre[rb + i] = ar[i]; sim[rb + i] = ai[i]; }
  }
  __syncthreads();

  // ---- epilogue: out0=Re(Q), out1=Im(Q), out2=Re/Im(R); window + mean ----
  for (int jj = t; jj < 12288; jj += 256) {
    const int x2 = jj & 31, y2 = (jj >> 5) & 31;
    const int rest = jj >> 10;          // 0..11, wave-uniform
    const int p = rest & 3, c = rest >> 2;
    const int ppy = pgeo[p*4+0], ppx = pgeo[p*4+1], pb = pgeo[p*4+2];
    const int oy = ppy * 8 + y2 - 32, ox = ppx * 8 + x2 - 32;
    if (oy >= 0 && oy < 512 && ox >= 0 && ox < 512) {
      const int l = y2 * LSTR + x2;
      float v;
      if (c == 0)      v = sre[p * PL + l];
      else if (c == 1) v = sim[p * PL + l];
      else             v = ((p & 1) ? sim : sre)[(4 + (p >> 1)) * PL + l];
      const float wv = w1[y2] * w1[x2];               // win == win_interp
      const float mc = red[p*6 + c] * (1.f/1024.f);
      const float val = (v * (1.f/6144.f) + mc * wv) * wv;
      const size_t off = (((size_t)pb * 3 + c) * 512 + oy) * 512 + ox;
      if (MODE == 1) dst[(size_t)pgeo[p*4+3] * PLANE_FLOATS + off] = val;
      else           atomicAdd(dst + off, val);
    }
  }
}

// mask(y,x) = mrow(y%8) * mrow(x%8), mrow(r) = sum_k w1[r+8k]^2
__device__ __forceinline__ float mask_row(int r) {
  float m = 0.f;
  #pragma unroll
  for (int k = 0; k < 4; ++k) {
    float tt = (float)(r + 8 * k) - 15.5f;
    float w = __expf(tt * tt * INV_WIN_DEN);
    m += w * w;
  }
  return m;
}

// MODE1 phase 2: out = (sum of 16 planes + eps) / (mask + eps)
__global__ void wiener_combine(const float* __restrict__ ws, float* __restrict__ out)
{
  const int i = blockIdx.x * 256 + threadIdx.x;   // out_size = 3,145,728
  const int xx = i & 511;
  const int yy = (i >> 9) & 511;
  float s = 0.f;
  #pragma unroll
  for (int p = 0; p < 16; ++p) s += ws[(size_t)p * PLANE_FLOATS + i];
  out[i] = (s + EPSF) / (mask_row(yy & 7) * mask_row(xx & 7) + EPSF);
}

// MODE0 phase 2: in-place normalize after atomic accumulation
__global__ void wiener_norm(float* __restrict__ out)
{
  const int i = blockIdx.x * 256 + threadIdx.x;
  const int xx = i & 511;
  const int yy = (i >> 9) & 511;
  out[i] = (out[i] + EPSF) / (mask_row(yy & 7) * mask_row(xx & 7) + EPSF);
}

extern "C" void kernel_launch(void* const* d_in, const int* in_sizes, int n_in,
                              void* d_out, int out_size, void* d_ws, size_t ws_size,
                              hipStream_t stream)
{
  const float* I = (const float*)d_in[0];
  const float* S = (const float*)d_in[1];
  float* out = (float*)d_out;
  const int nblocks = (4 * 67 * 67) / 4;   // 4 patches per block, 4489 blocks

  if (ws_size >= WS_NEEDED && d_ws != nullptr) {
    float* ws = (float*)d_ws;
    // every in-crop plane pixel is written exactly once -> no zeroing needed
    wiener_patch<1><<<dim3(nblocks), dim3(256), 0, stream>>>(I, S, ws);
    wiener_combine<<<dim3(out_size / 256), dim3(256), 0, stream>>>(ws, out);
  } else {
    hipMemsetAsync(out, 0, (size_t)out_size * sizeof(float), stream);
    wiener_patch<0><<<dim3(nblocks), dim3(256), 0, stream>>>(I, S, out);
    wiener_norm<<<dim3(out_size / 256), dim3(256), 0, stream>>>(out);
  }
}